// Round 1
// baseline (246.338 us; speedup 1.0000x reference)
//
#include <hip/hip_runtime.h>

#define NN 50000
#define NE 800000

// ---------------- GEMM: X = nodes @ W + b_lin  (fp32, [NN,128] @ [128,128]) ---
__global__ __launch_bounds__(256) void gemm_bias(
    const float* __restrict__ A,   // nodes [NN][128]
    const float* __restrict__ W,   // [128][128]
    const float* __restrict__ bl,  // [128]
    float* __restrict__ X)         // [NN][128]
{
    __shared__ float As[32][68];    // transposed A tile: As[k][row]
    __shared__ float Bs[32][132];   // B tile: Bs[k][col]
    const int tid = threadIdx.x;
    const int tx = tid & 15, ty = tid >> 4;
    const int r0 = blockIdx.x * 64;
    float acc[4][8];
#pragma unroll
    for (int i = 0; i < 4; ++i)
#pragma unroll
        for (int j = 0; j < 8; ++j) acc[i][j] = 0.f;

    for (int k0 = 0; k0 < 128; k0 += 32) {
#pragma unroll
        for (int l = 0; l < 2; ++l) {
            int id = tid + l * 256;
            int row = id >> 3, c4 = id & 7;
            int gr = r0 + row;
            float4 v = make_float4(0.f, 0.f, 0.f, 0.f);
            if (gr < NN) v = *(const float4*)(A + gr * 128 + k0 + c4 * 4);
            As[c4 * 4 + 0][row] = v.x; As[c4 * 4 + 1][row] = v.y;
            As[c4 * 4 + 2][row] = v.z; As[c4 * 4 + 3][row] = v.w;
        }
#pragma unroll
        for (int l = 0; l < 4; ++l) {
            int id = tid + l * 256;
            int kk = id >> 5, c4 = id & 31;
            *(float4*)&Bs[kk][c4 * 4] = *(const float4*)(W + (k0 + kk) * 128 + c4 * 4);
        }
        __syncthreads();
#pragma unroll
        for (int kk = 0; kk < 32; ++kk) {
            float4 a4 = *(float4*)&As[kk][ty * 4];
            float4 b0 = *(float4*)&Bs[kk][tx * 4];
            float4 b1 = *(float4*)&Bs[kk][64 + tx * 4];
            float av[4] = {a4.x, a4.y, a4.z, a4.w};
            float bv[8] = {b0.x, b0.y, b0.z, b0.w, b1.x, b1.y, b1.z, b1.w};
#pragma unroll
            for (int i = 0; i < 4; ++i)
#pragma unroll
                for (int j = 0; j < 8; ++j)
                    acc[i][j] = fmaf(av[i], bv[j], acc[i][j]);
        }
        __syncthreads();
    }
    float bloc[8];
#pragma unroll
    for (int j = 0; j < 4; ++j) { bloc[j] = bl[tx * 4 + j]; bloc[4 + j] = bl[64 + tx * 4 + j]; }
#pragma unroll
    for (int i = 0; i < 4; ++i) {
        int gr = r0 + ty * 4 + i;
        if (gr >= NN) continue;
        float4 o0 = make_float4(acc[i][0] + bloc[0], acc[i][1] + bloc[1],
                                acc[i][2] + bloc[2], acc[i][3] + bloc[3]);
        float4 o1 = make_float4(acc[i][4] + bloc[4], acc[i][5] + bloc[5],
                                acc[i][6] + bloc[6], acc[i][7] + bloc[7]);
        *(float4*)(X + gr * 128 + tx * 4) = o0;
        *(float4*)(X + gr * 128 + 64 + tx * 4) = o1;
    }
}

// ------------- per-node attention scalars: a0 = lrelu(x[:, :64]·α0), a1 = lrelu(x[:,64:]·α1)
__global__ __launch_bounds__(256) void node_alpha(
    const float* __restrict__ X, const float* __restrict__ alpha,
    float* __restrict__ a0, float* __restrict__ a1)
{
    int n = blockIdx.x * 4 + (threadIdx.x >> 6);
    int lane = threadIdx.x & 63;
    if (n >= NN) return;
    float v0 = X[n * 128 + lane] * alpha[lane];
    float v1 = X[n * 128 + 64 + lane] * alpha[64 + lane];
#pragma unroll
    for (int d = 1; d < 64; d <<= 1) {
        v0 += __shfl_xor(v0, d);
        v1 += __shfl_xor(v1, d);
    }
    if (lane == 0) {
        a0[n] = (v0 > 0.f) ? v0 : 0.2f * v0;
        a1[n] = (v1 > 0.f) ? v1 : 0.2f * v1;
    }
}

// ------------- CSR build ------------------------------------------------------
__global__ void hist(const int* __restrict__ rcv, int* __restrict__ cnt)
{
    for (int i = blockIdx.x * blockDim.x + threadIdx.x; i < NE; i += gridDim.x * blockDim.x)
        atomicAdd(&cnt[rcv[i]], 1);
}

__global__ __launch_bounds__(1024) void exscan(int* __restrict__ cnt, int* __restrict__ off)
{
    __shared__ int wsum[17];
    const int t = threadIdx.x;
    const int lane = t & 63, wid = t >> 6;
    int run = 0;
    for (int base = 0; base < NN; base += 1024) {
        int i = base + t;
        int v = (i < NN) ? cnt[i] : 0;
        int incl = v;
#pragma unroll
        for (int d = 1; d < 64; d <<= 1) {
            int u = __shfl_up(incl, d);
            if (lane >= d) incl += u;
        }
        if (lane == 63) wsum[wid] = incl;
        __syncthreads();
        if (wid == 0 && lane < 16) {
            int wv = wsum[lane];
            int wincl = wv;
#pragma unroll
            for (int d = 1; d < 16; d <<= 1) {
                int u = __shfl_up(wincl, d);
                if (lane >= d) wincl += u;
            }
            wsum[lane] = wincl - wv;           // exclusive wave offset
            if (lane == 15) wsum[16] = wincl;  // chunk total
        }
        __syncthreads();
        if (i < NN) { off[i] = run + wsum[wid] + (incl - v); cnt[i] = 0; }
        int tot = wsum[16];
        __syncthreads();
        run += tot;
    }
    if (t == 0) off[NN] = run;
}

__global__ void scatter(const int* __restrict__ snd, const int* __restrict__ rcv,
                        const int* __restrict__ off, int* __restrict__ cur,
                        int* __restrict__ srt)
{
    for (int i = blockIdx.x * blockDim.x + threadIdx.x; i < NE; i += gridDim.x * blockDim.x) {
        int r = rcv[i];
        int p = off[r] + atomicAdd(&cur[r], 1);
        srt[p] = snd[i];
    }
}

// ------------- per-node aggregation: softmax (heads 0/1) + mean (heads 2/3) ---
__global__ __launch_bounds__(64) void aggregate(
    const float* __restrict__ X,
    const float* __restrict__ a0, const float* __restrict__ a1,
    const int* __restrict__ off, const int* __restrict__ srt,
    const float* __restrict__ bias, float* __restrict__ out)
{
    const int n = blockIdx.x;
    const int lane = threadIdx.x;
    const int beg = off[n], end = off[n + 1];
    const float a0n = a0[n], a1n = a1[n];

    // pass 1: segment max over {self} ∪ neighbors
    float m0 = a0n, m1 = a1n;
    for (int j = beg + lane; j < end; j += 64) {
        int s = srt[j];
        m0 = fmaxf(m0, a0[s]);
        m1 = fmaxf(m1, a1[s]);
    }
#pragma unroll
    for (int d = 1; d < 64; d <<= 1) {
        m0 = fmaxf(m0, __shfl_xor(m0, d));
        m1 = fmaxf(m1, __shfl_xor(m1, d));
    }

    // pass 2: weighted accumulation. lane = channel c (heads 0/1 at c, heads 2/3 at 64+c)
    float accA = 0.f, accB = 0.f, D0 = 0.f, D1 = 0.f;
    for (int j = beg; j < end; ++j) {
        int s = srt[j];                       // lane-uniform broadcast load
        float w0 = __expf(a0[s] - m0);
        float w1 = __expf(a1[s] - m1);
        float x1 = X[s * 128 + lane];
        float x2 = X[s * 128 + 64 + lane];
        accA = fmaf((lane < 32) ? w0 : w1, x1, accA);
        accB += x2;
        D0 += w0; D1 += w1;
    }
    // self loop
    {
        float w0 = __expf(a0n - m0);
        float w1 = __expf(a1n - m1);
        accA = fmaf((lane < 32) ? w0 : w1, X[n * 128 + lane], accA);
        accB += X[n * 128 + 64 + lane];
        D0 += w0; D1 += w1;
    }
    float invdeg = 1.f / (float)(end - beg + 1);
    out[n * 128 + lane] = accA / ((lane < 32) ? D0 : D1) + bias[lane];
    out[n * 128 + 64 + lane] = accB * invdeg + bias[64 + lane];
}

// ------------------------------------------------------------------------------
extern "C" void kernel_launch(void* const* d_in, const int* in_sizes, int n_in,
                              void* d_out, int out_size, void* d_ws, size_t ws_size,
                              hipStream_t stream)
{
    const float* nodes     = (const float*)d_in[0];
    const int*   senders   = (const int*)d_in[1];
    const int*   receivers = (const int*)d_in[2];
    const float* W         = (const float*)d_in[3];
    const float* b_lin     = (const float*)d_in[4];
    const float* alpha     = (const float*)d_in[5];
    const float* bias      = (const float*)d_in[6];
    float* out = (float*)d_out;

    char* ws = (char*)d_ws;
    float* X   = (float*)(ws);                 // 25,600,000 B
    float* a0  = (float*)(ws + 25600000);      // 200,000 B
    float* a1  = (float*)(ws + 25800000);      // 200,000 B
    int*   cnt = (int*)  (ws + 26000000);      // 200,000 B
    int*   off = (int*)  (ws + 26200000);      // 200,004 B (padded)
    int*   srt = (int*)  (ws + 26400064);      // 3,200,000 B

    hipMemsetAsync(cnt, 0, NN * sizeof(int), stream);
    gemm_bias <<<(NN + 63) / 64, 256, 0, stream>>>(nodes, W, b_lin, X);
    node_alpha<<<(NN + 3) / 4, 256, 0, stream>>>(X, alpha, a0, a1);
    hist      <<<1024, 256, 0, stream>>>(receivers, cnt);
    exscan    <<<1, 1024, 0, stream>>>(cnt, off);
    scatter   <<<1024, 256, 0, stream>>>(senders, receivers, off, cnt, srt);
    aggregate <<<NN, 64, 0, stream>>>(X, a0, a1, off, srt, bias, out);
}